// Round 6
// baseline (195.108 us; speedup 1.0000x reference)
//
#include <hip/hip_runtime.h>
#include <math.h>

// ConvBertLightConv: dynamic depthwise conv with softmax-normalized per-(pos,head) kernels.
// B=8, S=4096, D=768 (12 heads x 64), K=9, 'same' zero padding along S.
// out[b,s,h,d] = sum_k softmax(filters[b,s,h,:])[k] * x[b, s+k-4, h*64+d]
//
// R8: occupancy-scaling attack. Pooled R2/R3/R5/R7 evidence: chip BW scales
// LINEARLY with resident waves (~0.7-1.2 GB/s per wave); per-wave pipeline
// depth (R5 gll burst, R7 counted-vmcnt) bought ~1.5x per-wave but halved
// occupancy -> net loss. So: take R3's structure (best BW/wave, proven) and
// max out waves/CU:
//  - TTILE 16->8: grid 4096 blocks; launch_bounds(192,8) -> nominal 30
//    waves/CU (94% of the 32-wave cap) vs R3's 24-cap/45%-measured.
//    R3 compiled to 32 VGPR, comfortably under the 64-VGPR 8-wave ceiling.
//  - x over-fetch rises to 2x at cache level, but x is L3-resident across
//    bench iterations (FETCH 65-80 MB < x size already) -> non-binding.
//  - XCD-aware bijective swizzle (4096 % 8 == 0): wg = (bid&7)*512 + (bid>>3)
//    gives XCD k batch k's chunks IN ORDER -> 8-row inter-chunk halos become
//    same-XCD L2 hits instead of cross-XCD dup fetches.
//  - filter tile (864 floats) staged coalesced to LDS; one softmax per
//    (s,head) pair (96 pairs); conv reads weights via LDS broadcast.

#define KS 9
#define HD 64
#define NH 12
#define DMODEL 768              // NH*HD
#define SEQ 4096
#define BATCH 8
#define TTILE 8                 // s-positions per block
#define CHUNKS (SEQ / TTILE)    // 512
#define FSTRIDE (NH * KS)       // 108 filter floats per position
#define FTILE (TTILE * FSTRIDE) // 864 floats
#define NPAIRS (TTILE * NH)     // 96 (s,head) pairs per block
#define NTHREADS 192

__global__ __launch_bounds__(NTHREADS, 8) void lightconv_kernel(
    const float* __restrict__ x,      // [B, S, 768]
    const float* __restrict__ filt,   // [B, S, 108]
    float* __restrict__ out)          // [B, S, 768]
{
    __shared__ float wlds[FTILE];             // 3456 B

    // XCD-aware swizzle (blocks issue to XCDs round-robin by blockIdx):
    // XCD k owns contiguous work [k*512, (k+1)*512) = all 512 chunks of
    // batch k, visited in s-order -> halo rows L2-hit on the same XCD.
    const int bid   = blockIdx.x;
    const int wg    = (bid & 7) * ((BATCH * CHUNKS) / 8) + (bid >> 3);
    const int chunk = wg & (CHUNKS - 1);
    const int b     = wg >> 9;                // CHUNKS = 512
    const int s0    = chunk * TTILE;
    const int t     = threadIdx.x;            // 0..191

    // ---- Phase 1: coalesced stage of filter tile [8][108] into LDS ----
    const float* fbase = filt + ((size_t)b * SEQ + s0) * FSTRIDE;
#pragma unroll
    for (int i = 0; i < 5; ++i) {             // ceil(864/192)
        const int idx = t + i * NTHREADS;
        if (idx < FTILE) wlds[idx] = fbase[idx];
    }
    __syncthreads();

    // ---- Phase 2: one softmax per (s_local, head); 96 pairs ----
    if (t < NPAIRS) {
        const int sl = t & 7;                 // s_local 0..7
        const int hh = t >> 3;                // head    0..11
        float* wp = &wlds[sl * FSTRIDE + hh * KS];
        float w[KS];
        float m = -1e30f;
#pragma unroll
        for (int k = 0; k < KS; ++k) { w[k] = wp[k]; m = fmaxf(m, w[k]); }
        float sum = 0.f;
#pragma unroll
        for (int k = 0; k < KS; ++k) { w[k] = __expf(w[k] - m); sum += w[k]; }
        const float inv = 1.0f / sum;
#pragma unroll
        for (int k = 0; k < KS; ++k) wp[k] = w[k] * inv;
    }
    __syncthreads();

    // ---- Phase 3: sliding-window conv, 9-row window in registers ----
    const int head = t >> 4;                  // 0..11
    const int d4   = (t & 15) << 2;           // 0,4,...,60

    const float* xc = x   + (size_t)b * SEQ * DMODEL + head * HD + d4;
    float*       oc = out + (size_t)b * SEQ * DMODEL + head * HD + d4;

    const float4 zero = make_float4(0.f, 0.f, 0.f, 0.f);

    float4 win[KS];
#pragma unroll
    for (int k = 0; k < KS - 1; ++k) {        // rows s0-4 .. s0+3
        const int ss = s0 + k - (KS / 2);     // ss <= s0+3 < SEQ always
        win[k] = (ss >= 0) ? *reinterpret_cast<const float4*>(xc + (size_t)ss * DMODEL)
                           : zero;
    }

#pragma unroll
    for (int i = 0; i < TTILE; ++i) {
        const int s  = s0 + i;
        const int ss = s + (KS / 2);          // new trailing row
        win[KS - 1] = (ss < SEQ) ? *reinterpret_cast<const float4*>(xc + (size_t)ss * DMODEL)
                                 : zero;

        const float* wp = &wlds[i * FSTRIDE + head * KS];  // 16-lane broadcast

        float4 acc = zero;
#pragma unroll
        for (int k = 0; k < KS; ++k) {
            const float wk = wp[k];
            acc.x += wk * win[k].x;
            acc.y += wk * win[k].y;
            acc.z += wk * win[k].z;
            acc.w += wk * win[k].w;
        }
        *reinterpret_cast<float4*>(oc + (size_t)s * DMODEL) = acc;

#pragma unroll
        for (int k = 0; k < KS - 1; ++k) win[k] = win[k + 1];
    }
}

extern "C" void kernel_launch(void* const* d_in, const int* in_sizes, int n_in,
                              void* d_out, int out_size, void* d_ws, size_t ws_size,
                              hipStream_t stream) {
    const float* x    = (const float*)d_in[0];   // [8,4096,768] fp32
    const float* filt = (const float*)d_in[1];   // [8,4096,108] fp32
    float* out        = (float*)d_out;           // [8,4096,12,64] fp32

    const int grid = BATCH * CHUNKS;             // 8 * 512 = 4096 blocks
    lightconv_kernel<<<grid, NTHREADS, 0, stream>>>(x, filt, out);
}